// Round 1
// baseline (45.988 us; speedup 1.0000x reference)
//
#include <hip/hip_runtime.h>
#include <hip/hip_bf16.h>
#include <stdint.h>

// Conv2d, B=32, Cin=64, Cout=128, 3x3, stride 1, pad 1, H=W=56, fp32 in/out.
// Reference has mismatched flatten orders -> equivalent to standard conv with
// permuted weights: Weff for patch elem (c,di,dj) is K[f/192][(f%192)/64][f%64]
// with f = c*9 + di*3 + dj.

#define B_   32
#define CIN  64
#define COUT 128
#define H_   56
#define HP   58          // spatially padded (pad=1 each side)
#define F_   576         // 9*64 reduction length

typedef __attribute__((ext_vector_type(8))) short bf16x8;
typedef __attribute__((ext_vector_type(4))) float f32x4;

#define XP_ELEMS (B_*HP*HP*CIN)          // 6,889,472
#define XP_SLACK 4096                    // zero slack for tail-row overreads
#define XP_TOTAL (XP_ELEMS + XP_SLACK)
#define WG_ELEMS (COUT*F_)               // 73,728
#define WS_NEEDED ((size_t)(XP_TOTAL + WG_ELEMS) * 2)

// ---------- prepass 1: x NCHW f32 -> padded NHWC bf16 xpT[b][h][w][c] ----------
__global__ __launch_bounds__(256) void prep_x(const float* __restrict__ x,
                                              __hip_bfloat16* __restrict__ xpT) {
  const int id = blockIdx.x;
  const int t  = threadIdx.x;
  if (id >= B_*HP) {                     // slack zero-fill block
    for (int idx = t; idx < XP_SLACK; idx += 256)
      xpT[XP_ELEMS + idx] = __float2bfloat16(0.f);
    return;
  }
  const int b = id / HP, h = id % HP;
  __hip_bfloat16* orow = xpT + (size_t)(b*HP + h) * HP * CIN;
  if (h == 0 || h == HP-1) {             // top/bottom pad rows
    for (int idx = t; idx < HP*CIN; idx += 256) orow[idx] = __float2bfloat16(0.f);
    return;
  }
  __shared__ float tile[CIN][H_ + 1];    // +1 pad: conflict-free transpose
  const float* xrow = x + ((size_t)(b*CIN)*H_ + (h-1)) * H_;
  for (int idx = t; idx < CIN*H_; idx += 256) {
    int c = idx / H_, w = idx % H_;
    tile[c][w] = xrow[(size_t)c*H_*H_ + w];   // coalesced along w
  }
  __syncthreads();
  for (int idx = t; idx < HP*CIN; idx += 256) {
    int w = idx >> 6, c = idx & 63;           // coalesced along c on write
    float v = (w == 0 || w == HP-1) ? 0.f : tile[c][w-1];
    orow[idx] = __float2bfloat16(v);
  }
}

// ---------- prepass 2: K[kh][kw][cin][cout] f32 -> WgT[co][g] bf16 ----------
// g = di*192 + dj*64 + c  (reduction reorder); value = Kf[f(g)][co], f = c*9+di*3+dj
__global__ __launch_bounds__(256) void prep_w(const float* __restrict__ K,
                                              __hip_bfloat16* __restrict__ WgT) {
  int n = blockIdx.x*256 + threadIdx.x;
  if (n >= WG_ELEMS) return;
  int co = n / F_, g = n % F_;
  int di = g / 192, dj = (g % 192) / 64, c = g & 63;
  int f  = c*9 + di*3 + dj;
  int kh = f / 192, kw = (f % 192) / 64, cc = f & 63;
  float v = K[(((size_t)kh*3 + kw)*CIN + cc)*COUT + co];
  WgT[n] = __float2bfloat16(v);
}

// ---------- main: implicit GEMM, block = one (b,i) row, tile 64x128 ----------
// LDS layout (bytes): A[2][8192] at 0, B[2][16384] at 16384.  48 KiB total.
// XOR swizzle byte^=((row&7)<<4) applied on global SOURCE (linear LDS dest for
// global_load_lds) and identically on ds_read addresses (rule #21).
__global__ __launch_bounds__(256, 2) void conv_mfma(
    const __hip_bfloat16* __restrict__ xpT,
    const __hip_bfloat16* __restrict__ WgT,
    float* __restrict__ out) {
  __shared__ __align__(16) char lds[49152];
  const int t    = threadIdx.x;
  const int wave = t >> 6;
  const int l    = t & 63;
  const int lr   = l & 15, lq = l >> 4;
  const int wr   = wave >> 1, wc = wave & 1;   // 2x2 wave grid
  const int bb   = blockIdx.x / H_;
  const int i    = blockIdx.x % H_;

  f32x4 acc[2][4];
#pragma unroll
  for (int mi = 0; mi < 2; ++mi)
#pragma unroll
    for (int ni = 0; ni < 4; ++ni) acc[mi][ni] = (f32x4)0.f;

  const char* wbase = (const char*)WgT;

  auto stage = [&](int q, int buf) {
    const int di = q / 3, dj = q % 3;
    // A chunk: one contiguous 8KB span: xpT[bb][i+di][dj .. dj+63][0..63]
    const char* ag = (const char*)(xpT + ((size_t)(bb*HP + (i + di))*HP + dj) * CIN);
    char* Ab = lds + buf*8192;
    char* Bb = lds + 16384 + buf*16384;
#pragma unroll
    for (int s = 0; s < 2; ++s) {
      int o = s*4096 + t*16;                       // linear LDS byte offset
      int m = o >> 7;                              // 128B rows
      int src = (o & ~127) | ((o & 127) ^ ((m & 7) << 4));   // pre-swizzled src
      __builtin_amdgcn_global_load_lds(
          (const __attribute__((address_space(1))) void*)(ag + src),
          (__attribute__((address_space(3))) void*)(Ab + s*4096 + wave*1024),
          16, 0, 0);
    }
    // B chunk: WgT[co][q*64 .. q*64+63], row stride 1152B
    const char* wg = wbase + q*128;
#pragma unroll
    for (int s = 0; s < 4; ++s) {
      int o = s*4096 + t*16;
      int co = o >> 7;
      int scb = (o & 127) ^ ((co & 7) << 4);
      __builtin_amdgcn_global_load_lds(
          (const __attribute__((address_space(1))) void*)(wg + (size_t)co*1152 + scb),
          (__attribute__((address_space(3))) void*)(Bb + s*4096 + wave*1024),
          16, 0, 0);
    }
  };

  stage(0, 0);
  __syncthreads();

  for (int q = 0; q < 9; ++q) {
    const int buf = q & 1;
    if (q + 1 < 9) stage(q + 1, buf ^ 1);          // prefetch next chunk
    const char* Ab = lds + buf*8192;
    const char* Bb = lds + 16384 + buf*16384;
#pragma unroll
    for (int ks = 0; ks < 2; ++ks) {
      bf16x8 a[2], bfr[4];
      const int cb = ks*64 + lq*16;
#pragma unroll
      for (int mi = 0; mi < 2; ++mi) {
        int m = wr*32 + mi*16 + lr;
        int addr = ((m << 7) | cb) ^ ((m & 7) << 4);
        a[mi] = *(const bf16x8*)(Ab + addr);
      }
#pragma unroll
      for (int ni = 0; ni < 4; ++ni) {
        int co = wc*64 + ni*16 + lr;
        int addr = ((co << 7) | cb) ^ ((co & 7) << 4);
        bfr[ni] = *(const bf16x8*)(Bb + addr);
      }
#pragma unroll
      for (int mi = 0; mi < 2; ++mi)
#pragma unroll
        for (int ni = 0; ni < 4; ++ni)
          acc[mi][ni] = __builtin_amdgcn_mfma_f32_16x16x32_bf16(
              a[mi], bfr[ni], acc[mi][ni], 0, 0, 0);
    }
    __syncthreads();
  }

  // epilogue: C/D layout col=lane&15, row=(lane>>4)*4+reg  -> j = row, co = col
#pragma unroll
  for (int mi = 0; mi < 2; ++mi) {
    int j0 = wr*32 + mi*16 + lq*4;
    if (j0 < H_) {
#pragma unroll
      for (int ni = 0; ni < 4; ++ni) {
        int co = wc*64 + ni*16 + lr;
        float* dst = out + (((size_t)(bb*COUT + co))*H_ + i)*H_ + j0;
        *(f32x4*)dst = acc[mi][ni];
      }
    }
  }
}

// ---------- fallback (only if workspace too small): naive fp32 direct ----------
__global__ __launch_bounds__(256) void conv_naive(const float* __restrict__ x,
                                                  const float* __restrict__ K,
                                                  float* __restrict__ out) {
  int idx = blockIdx.x*256 + threadIdx.x;
  const int total = B_*COUT*H_*H_;
  if (idx >= total) return;
  int j = idx % H_, i = (idx / H_) % H_, co = (idx / (H_*H_)) % COUT, b = idx / (H_*H_*COUT);
  float s = 0.f;
  for (int c = 0; c < CIN; ++c)
    for (int di = 0; di < 3; ++di) {
      int ii = i + di - 1;
      if (ii < 0 || ii >= H_) continue;
      for (int dj = 0; dj < 3; ++dj) {
        int jj = j + dj - 1;
        if (jj < 0 || jj >= H_) continue;
        int f = c*9 + di*3 + dj;
        int kh = f / 192, kw = (f % 192) / 64, cc = f & 63;
        s += x[(((size_t)b*CIN + c)*H_ + ii)*H_ + jj] *
             K[(((size_t)kh*3 + kw)*CIN + cc)*COUT + co];
      }
    }
  out[idx] = s;
}

extern "C" void kernel_launch(void* const* d_in, const int* in_sizes, int n_in,
                              void* d_out, int out_size, void* d_ws, size_t ws_size,
                              hipStream_t stream) {
  const float* x = (const float*)d_in[0];
  const float* K = (const float*)d_in[1];
  float* out = (float*)d_out;
  if (ws_size >= WS_NEEDED) {
    __hip_bfloat16* xpT = (__hip_bfloat16*)d_ws;
    __hip_bfloat16* WgT = xpT + XP_TOTAL;
    prep_x<<<B_*HP + 1, 256, 0, stream>>>(x, xpT);
    prep_w<<<(WG_ELEMS + 255)/256, 256, 0, stream>>>(K, WgT);
    conv_mfma<<<B_*H_, 256, 0, stream>>>(xpT, WgT, out);
  } else {
    conv_naive<<<(B_*COUT*H_*H_ + 255)/256, 256, 0, stream>>>(x, K, out);
  }
}

// Round 2
// 42.860 us; speedup vs baseline: 1.0730x; 1.0730x over previous
//
#include <hip/hip_runtime.h>
#include <hip/hip_bf16.h>
#include <stdint.h>

// Conv2d, B=32, Cin=64, Cout=128, 3x3, stride 1, pad 1, H=W=56, fp32 in/out.
// Reference's mismatched flatten == standard conv with permuted weights:
// Weff for patch elem (c,di,dj) = K[f/192][(f%192)/64][f%64], f = c*9+di*3+dj.

#define B_   32
#define CIN  64
#define COUT 128
#define H_   56
#define HP   58          // spatially padded (pad=1 each side)
#define F_   576         // 9*64 reduction length

typedef __attribute__((ext_vector_type(8))) short bf16x8;
typedef __attribute__((ext_vector_type(4))) float f32x4;

#define XP_ELEMS (B_*HP*HP*CIN)          // 6,889,472
#define XP_SLACK 4096                    // zero slack for tail overreads
#define XP_TOTAL (XP_ELEMS + XP_SLACK)
#define WG_ELEMS (COUT*F_)               // 73,728
#define WS_NEEDED ((size_t)(XP_TOTAL + WG_ELEMS) * 2)

#define NROW   (B_*HP)                   // 1856 x-row blocks
#define NWBLK  (WG_ELEMS/256)            // 288 weight blocks

// ---------- fused prepass: x NCHW f32 -> padded NHWC bf16; K -> WgT[co][g] ----
__global__ __launch_bounds__(256) void prep_all(const float* __restrict__ x,
                                                const float* __restrict__ K,
                                                __hip_bfloat16* __restrict__ xpT,
                                                __hip_bfloat16* __restrict__ WgT) {
  const int id = blockIdx.x;
  const int t  = threadIdx.x;

  if (id > NROW) {                       // ---- weight permute blocks ----
    int n = (id - (NROW + 1))*256 + t;   // n < WG_ELEMS always (288 full blocks)
    int co = n / F_, g = n % F_;
    int di = g / 192, dj = (g % 192) / 64, c = g & 63;
    int f  = c*9 + di*3 + dj;
    int kh = f / 192, kw = (f % 192) / 64, cc = f & 63;
    WgT[n] = __float2bfloat16(K[(((size_t)kh*3 + kw)*CIN + cc)*COUT + co]);
    return;
  }
  if (id == NROW) {                      // ---- slack zero-fill ----
    bf16x8 z = (bf16x8)0;
    for (int idx = t; idx < XP_SLACK/8; idx += 256)
      ((bf16x8*)(xpT + XP_ELEMS))[idx] = z;
    return;
  }

  const int b = id / HP, h = id % HP;
  __hip_bfloat16* orow = xpT + (size_t)(b*HP + h) * HP * CIN;
  if (h == 0 || h == HP-1) {             // top/bottom pad rows
    bf16x8 z = (bf16x8)0;
    for (int idx = t; idx < HP*CIN/8; idx += 256) ((bf16x8*)orow)[idx] = z;
    return;
  }
  __shared__ __align__(16) float tile[CIN][60];   // 60: rows 16B-aligned
  const float* xrow = x + ((size_t)(b*CIN)*H_ + (h-1)) * H_;
  for (int idx = t; idx < CIN*(H_/4); idx += 256) {        // float4 reads
    int c = idx / 14, w4 = idx % 14;
    f32x4 v = *(const f32x4*)(xrow + (size_t)c*H_*H_ + w4*4);
    *(f32x4*)&tile[c][w4*4] = v;
  }
  __syncthreads();
  for (int idx = t; idx < HP*8; idx += 256) {              // bf16x8 writes
    int w = idx >> 3, cg = (idx & 7) * 8;
    __align__(16) __hip_bfloat16 tmp[8];
    if (w == 0 || w == HP-1) {
#pragma unroll
      for (int k2 = 0; k2 < 8; ++k2) tmp[k2] = __float2bfloat16(0.f);
    } else {
#pragma unroll
      for (int k2 = 0; k2 < 8; ++k2) tmp[k2] = __float2bfloat16(tile[cg + k2][w-1]);
    }
    *(bf16x8*)(orow + (size_t)w*CIN + cg) = *(const bf16x8*)tmp;
  }
}

// ---------- main: implicit GEMM, block = (b, 2 output rows), tile 128x128 ----
// LDS (bytes): buf k at k*32768: A 16KB, B 16KB.  64 KiB total, 2 blocks/CU.
// XOR swizzle byte^=((row&7)<<4): pre-swizzled global SOURCE (linear LDS dest
// for global_load_lds) + identically swizzled ds_read addresses (rule #21).
__global__ __launch_bounds__(256, 2) void conv_mfma(
    const __hip_bfloat16* __restrict__ xpT,
    const __hip_bfloat16* __restrict__ WgT,
    float* __restrict__ out) {
  __shared__ __align__(16) char lds[65536];
  const int t    = threadIdx.x;
  const int wave = t >> 6;
  const int l    = t & 63;
  const int lr   = l & 15, lq = l >> 4;
  const int wr   = wave >> 1, wc = wave & 1;       // 2x2 wave grid, 64x64 each

  // bijective XCD swizzle: 896 = 8 * 112; same-XCD neighbors share A rows
  const int bid = blockIdx.x;
  const int swz = (bid & 7) * 112 + (bid >> 3);
  const int bb  = swz / 28;
  const int i0  = (swz % 28) * 2;

  f32x4 acc[4][4];
#pragma unroll
  for (int mi = 0; mi < 4; ++mi)
#pragma unroll
    for (int ni = 0; ni < 4; ++ni) acc[mi][ni] = (f32x4)0.f;

  const char* xb    = (const char*)xpT + (size_t)bb*HP*HP*CIN*2;
  const char* wbase = (const char*)WgT;

  auto stage = [&](int q, int buf) {
    const int di = q / 3, dj = q % 3;
    char* Ab = lds + buf*32768;
    char* Bb = Ab + 16384;
    // A: rows 0..63 = output row i0, rows 64..127 = i0+1; 64 j's each
#pragma unroll
    for (int s = 0; s < 4; ++s) {
      int o = s*4096 + t*16;                       // linear LDS byte offset
      int m = o >> 7;                              // A row (128B rows)
      const char* src = xb
          + (size_t)((i0 + (m >> 6) + di)*HP + dj + (m & 63)) * (CIN*2)
          + ((o & 127) ^ ((m & 7) << 4));          // pre-swizzled source
      __builtin_amdgcn_global_load_lds(
          (const __attribute__((address_space(1))) void*)src,
          (__attribute__((address_space(3))) void*)(Ab + s*4096 + wave*1024),
          16, 0, 0);
    }
    // B: WgT[co][q*64 .. q*64+63], row stride 1152B
    const char* wg = wbase + q*128;
#pragma unroll
    for (int s = 0; s < 4; ++s) {
      int o  = s*4096 + t*16;
      int co = o >> 7;
      const char* src = wg + (size_t)co*1152 + ((o & 127) ^ ((co & 7) << 4));
      __builtin_amdgcn_global_load_lds(
          (const __attribute__((address_space(1))) void*)src,
          (__attribute__((address_space(3))) void*)(Bb + s*4096 + wave*1024),
          16, 0, 0);
    }
  };

  stage(0, 0);
  __syncthreads();

  for (int q = 0; q < 9; ++q) {
    const int buf = q & 1;
    if (q + 1 < 9) stage(q + 1, buf ^ 1);          // prefetch next chunk
    const char* Ab = lds + buf*32768;
    const char* Bb = Ab + 16384;
#pragma unroll
    for (int ks = 0; ks < 2; ++ks) {
      bf16x8 a[4], bfr[4];
      const int cb = ks*64 + lq*16;
#pragma unroll
      for (int mi = 0; mi < 4; ++mi) {
        int m = wr*64 + mi*16 + lr;
        a[mi] = *(const bf16x8*)(Ab + (((m << 7) | cb) ^ ((m & 7) << 4)));
      }
#pragma unroll
      for (int ni = 0; ni < 4; ++ni) {
        int co = wc*64 + ni*16 + lr;
        bfr[ni] = *(const bf16x8*)(Bb + (((co << 7) | cb) ^ ((co & 7) << 4)));
      }
#pragma unroll
      for (int mi = 0; mi < 4; ++mi)
#pragma unroll
        for (int ni = 0; ni < 4; ++ni)
          acc[mi][ni] = __builtin_amdgcn_mfma_f32_16x16x32_bf16(
              a[mi], bfr[ni], acc[mi][ni], 0, 0, 0);
    }
    __syncthreads();
  }

  // epilogue: C/D layout col=lane&15, row=(lane>>4)*4+reg; row->j, col->co
#pragma unroll
  for (int mi = 0; mi < 4; ++mi) {
    int j0 = mi*16 + lq*4;                          // m = wr*64 + j0
    if (j0 < H_) {
      int i = i0 + wr;
#pragma unroll
      for (int ni = 0; ni < 4; ++ni) {
        int co = wc*64 + ni*16 + lr;
        float* dst = out + (((size_t)(bb*COUT + co))*H_ + i)*H_ + j0;
        *(f32x4*)dst = acc[mi][ni];
      }
    }
  }
}

// ---------- fallback (workspace too small): naive fp32 direct ----------
__global__ __launch_bounds__(256) void conv_naive(const float* __restrict__ x,
                                                  const float* __restrict__ K,
                                                  float* __restrict__ out) {
  int idx = blockIdx.x*256 + threadIdx.x;
  const int total = B_*COUT*H_*H_;
  if (idx >= total) return;
  int j = idx % H_, i = (idx / H_) % H_, co = (idx / (H_*H_)) % COUT, b = idx / (H_*H_*COUT);
  float s = 0.f;
  for (int c = 0; c < CIN; ++c)
    for (int di = 0; di < 3; ++di) {
      int ii = i + di - 1;
      if (ii < 0 || ii >= H_) continue;
      for (int dj = 0; dj < 3; ++dj) {
        int jj = j + dj - 1;
        if (jj < 0 || jj >= H_) continue;
        int f = c*9 + di*3 + dj;
        int kh = f / 192, kw = (f % 192) / 64, cc = f & 63;
        s += x[(((size_t)b*CIN + c)*H_ + ii)*H_ + jj] *
             K[(((size_t)kh*3 + kw)*CIN + cc)*COUT + co];
      }
    }
  out[idx] = s;
}

extern "C" void kernel_launch(void* const* d_in, const int* in_sizes, int n_in,
                              void* d_out, int out_size, void* d_ws, size_t ws_size,
                              hipStream_t stream) {
  const float* x = (const float*)d_in[0];
  const float* K = (const float*)d_in[1];
  float* out = (float*)d_out;
  if (ws_size >= WS_NEEDED) {
    __hip_bfloat16* xpT = (__hip_bfloat16*)d_ws;
    __hip_bfloat16* WgT = xpT + XP_TOTAL;
    prep_all<<<NROW + 1 + NWBLK, 256, 0, stream>>>(x, K, xpT, WgT);
    conv_mfma<<<B_*28, 256, 0, stream>>>(xpT, WgT, out);
  } else {
    conv_naive<<<(B_*COUT*H_*H_ + 255)/256, 256, 0, stream>>>(x, K, out);
  }
}

// Round 3
// 40.927 us; speedup vs baseline: 1.1237x; 1.0472x over previous
//
#include <hip/hip_runtime.h>
#include <hip/hip_bf16.h>
#include <stdint.h>

// Conv2d, B=32, Cin=64, Cout=128, 3x3, stride 1, pad 1, H=W=56, fp32 in/out.
// Reference's mismatched flatten == standard conv with permuted weights:
// Weff for patch elem (c,di,dj) = K[f/192][(f%192)/64][f%64], f = c*9+di*3+dj.
// Reduction order g = di*192 + dj*64 + c  =>  for fixed di, A's K-slice is
// CONTIGUOUS in the padded-NHWC buffer: byte offset (j*64+k)*2 in row (i+di).

#define B_   32
#define CIN  64
#define COUT 128
#define H_   56
#define HP   58          // spatially padded (pad=1 each side)
#define F_   576         // 9*64 reduction length

typedef __attribute__((ext_vector_type(8))) short bf16x8;
typedef __attribute__((ext_vector_type(4))) float f32x4;

#define XP_ELEMS (B_*HP*HP*CIN)          // 6,889,472
#define XP_SLACK 4096                    // zero slack for tail overreads
#define XP_TOTAL (XP_ELEMS + XP_SLACK)
#define WG_ELEMS (COUT*F_)               // 73,728
#define WS_NEEDED ((size_t)(XP_TOTAL + WG_ELEMS) * 2)

#define NROW   (B_*HP)                   // 1856 x-row blocks
#define NWBLK  (WG_ELEMS/256)            // 288 weight blocks

// LDS map (bytes): A-once tile [0, 45568); B dbuf at 45568 + buf*16384.
#define A_STAGE 45056                    // 176 B/thread staged (44544 real)
#define A_ALLOC 45568
#define LDS_TOT (A_ALLOC + 2*16384)      // 78336 -> 2 blocks/CU

// ---------- fused prepass: x NCHW f32 -> padded NHWC bf16; K -> WgT[co][g] ----
__global__ __launch_bounds__(256) void prep_all(const float* __restrict__ x,
                                                const float* __restrict__ K,
                                                __hip_bfloat16* __restrict__ xpT,
                                                __hip_bfloat16* __restrict__ WgT) {
  const int id = blockIdx.x;
  const int t  = threadIdx.x;

  if (id > NROW) {                       // ---- weight permute blocks ----
    int n = (id - (NROW + 1))*256 + t;   // 288 full blocks
    int co = n / F_, g = n % F_;
    int di = g / 192, dj = (g % 192) / 64, c = g & 63;
    int f  = c*9 + di*3 + dj;
    int kh = f / 192, kw = (f % 192) / 64, cc = f & 63;
    WgT[n] = __float2bfloat16(K[(((size_t)kh*3 + kw)*CIN + cc)*COUT + co]);
    return;
  }
  if (id == NROW) {                      // ---- slack zero-fill ----
    bf16x8 z = (bf16x8)0;
    for (int idx = t; idx < XP_SLACK/8; idx += 256)
      ((bf16x8*)(xpT + XP_ELEMS))[idx] = z;
    return;
  }

  const int b = id / HP, h = id % HP;
  __hip_bfloat16* orow = xpT + (size_t)(b*HP + h) * HP * CIN;
  if (h == 0 || h == HP-1) {             // top/bottom pad rows
    bf16x8 z = (bf16x8)0;
    for (int idx = t; idx < HP*CIN/8; idx += 256) ((bf16x8*)orow)[idx] = z;
    return;
  }
  __shared__ __align__(16) float tile[CIN][60];   // 60: rows 16B-aligned
  const float* xrow = x + ((size_t)(b*CIN)*H_ + (h-1)) * H_;
  for (int idx = t; idx < CIN*(H_/4); idx += 256) {        // float4 reads
    int c = idx / 14, w4 = idx % 14;
    f32x4 v = *(const f32x4*)(xrow + (size_t)c*H_*H_ + w4*4);
    *(f32x4*)&tile[c][w4*4] = v;
  }
  __syncthreads();
  for (int idx = t; idx < HP*8; idx += 256) {              // bf16x8 writes
    int w = idx >> 3, cg = (idx & 7) * 8;
    __align__(16) __hip_bfloat16 tmp[8];
    if (w == 0 || w == HP-1) {
#pragma unroll
      for (int k2 = 0; k2 < 8; ++k2) tmp[k2] = __float2bfloat16(0.f);
    } else {
#pragma unroll
      for (int k2 = 0; k2 < 8; ++k2) tmp[k2] = __float2bfloat16(tile[cg + k2][w-1]);
    }
    *(bf16x8*)(orow + (size_t)w*CIN + cg) = *(const bf16x8*)tmp;
  }
}

// ---------- main: implicit GEMM, block = (b, 4 rows), M=256, N=128 ----------
// A staged ONCE per block (6 contiguous padded rows); only B double-buffered
// per 64-wide K chunk. XOR swizzle byte^=((row128&7)<<4): pre-swizzled global
// SOURCE (linear LDS dest for global_load_lds) + same XOR on ds_reads.
__global__ __launch_bounds__(256, 2) void conv_mfma(
    const __hip_bfloat16* __restrict__ xpT,
    const __hip_bfloat16* __restrict__ WgT,
    float* __restrict__ out) {
  __shared__ __align__(16) char lds[LDS_TOT];
  const int t    = threadIdx.x;
  const int wave = t >> 6;               // wave w -> output row i0+w
  const int l    = t & 63;
  const int lr   = l & 15, lq = l >> 4;

  // bijective XCD swizzle: 448 = 8 * 56
  const int bid = blockIdx.x;
  const int swz = (bid & 7) * 56 + (bid >> 3);
  const int bb  = swz / 14;
  const int i0  = (swz % 14) * 4;

  f32x4 acc[4][8];
#pragma unroll
  for (int mi = 0; mi < 4; ++mi)
#pragma unroll
    for (int ni = 0; ni < 8; ++ni) acc[mi][ni] = (f32x4)0.f;

  // A source: padded rows h = i0 .. i0+5, full width -> one contiguous span
  const char* xb    = (const char*)xpT + (size_t)(bb*HP + i0) * HP * CIN * 2;
  const char* wbase = (const char*)WgT;

  // ---- stage A once: 45056 B contiguous, swizzled source, linear dest ----
#pragma unroll
  for (int s = 0; s < 11; ++s) {
    int o = s*4096 + t*16;
    int m = o >> 7;
    const char* src = xb + ((o & ~127) | ((o & 127) ^ ((m & 7) << 4)));
    __builtin_amdgcn_global_load_lds(
        (const __attribute__((address_space(1))) void*)src,
        (__attribute__((address_space(3))) void*)(lds + s*4096 + wave*1024),
        16, 0, 0);
  }

  auto stageB = [&](int q, int buf) {    // 16 KB: WgT[co][q*64 .. +63]
    const char* wg = wbase + q*128;
    char* Bb = lds + A_ALLOC + buf*16384;
#pragma unroll
    for (int s = 0; s < 4; ++s) {
      int o  = s*4096 + t*16;
      int co = o >> 7;
      const char* src = wg + (size_t)co*1152 + ((o & 127) ^ ((co & 7) << 4));
      __builtin_amdgcn_global_load_lds(
          (const __attribute__((address_space(1))) void*)src,
          (__attribute__((address_space(3))) void*)(Bb + s*4096 + wave*1024),
          16, 0, 0);
    }
  };

  stageB(0, 0);
  __syncthreads();

#pragma unroll
  for (int q = 0; q < 9; ++q) {
    const int buf = q & 1;
    if (q < 8) stageB(q + 1, buf ^ 1);   // prefetch next B chunk
    const char* Bb = lds + A_ALLOC + buf*16384;
#pragma unroll
    for (int ks = 0; ks < 2; ++ks) {
      const int kg  = q*64 + ks*32;      // global k (compile-time)
      const int di  = kg / 192;
      const int rem = kg - di*192;       // k within di-slab
      bf16x8 a[4], bfr[8];
#pragma unroll
      for (int mi = 0; mi < 4; ++mi) {
        int r   = (wave + di)*58 + mi*16 + lr;       // A row (j = mi*16+lr)
        int tot = r*128 + rem*2 + lq*16;             // linear byte in A tile
        int adr = (tot & ~127) | ((tot & 127) ^ (((tot >> 7) & 7) << 4));
        a[mi] = *(const bf16x8*)(lds + adr);
      }
      const int cb = ks*64 + lq*16;
#pragma unroll
      for (int ni = 0; ni < 8; ++ni) {
        int co = ni*16 + lr;
        bfr[ni] = *(const bf16x8*)(Bb + (((co << 7) | cb) ^ ((co & 7) << 4)));
      }
#pragma unroll
      for (int mi = 0; mi < 4; ++mi)
#pragma unroll
        for (int ni = 0; ni < 8; ++ni)
          acc[mi][ni] = __builtin_amdgcn_mfma_f32_16x16x32_bf16(
              a[mi], bfr[ni], acc[mi][ni], 0, 0, 0);
    }
    __syncthreads();
  }

  // epilogue: C/D layout col=lane&15 -> co, row=(lane>>4)*4+reg -> j
  const int i = i0 + wave;
#pragma unroll
  for (int mi = 0; mi < 4; ++mi) {
    int j0 = mi*16 + lq*4;
    if (j0 < H_) {                       // j0 in {0..52}: j0+3 <= 55
#pragma unroll
      for (int ni = 0; ni < 8; ++ni) {
        int co = ni*16 + lr;
        float* dst = out + (((size_t)(bb*COUT + co))*H_ + i)*H_ + j0;
        *(f32x4*)dst = acc[mi][ni];
      }
    }
  }
}

// ---------- fallback (workspace too small): naive fp32 direct ----------
__global__ __launch_bounds__(256) void conv_naive(const float* __restrict__ x,
                                                  const float* __restrict__ K,
                                                  float* __restrict__ out) {
  int idx = blockIdx.x*256 + threadIdx.x;
  const int total = B_*COUT*H_*H_;
  if (idx >= total) return;
  int j = idx % H_, i = (idx / H_) % H_, co = (idx / (H_*H_)) % COUT, b = idx / (H_*H_*COUT);
  float s = 0.f;
  for (int c = 0; c < CIN; ++c)
    for (int di = 0; di < 3; ++di) {
      int ii = i + di - 1;
      if (ii < 0 || ii >= H_) continue;
      for (int dj = 0; dj < 3; ++dj) {
        int jj = j + dj - 1;
        if (jj < 0 || jj >= H_) continue;
        int f = c*9 + di*3 + dj;
        int kh = f / 192, kw = (f % 192) / 64, cc = f & 63;
        s += x[(((size_t)b*CIN + c)*H_ + ii)*H_ + jj] *
             K[(((size_t)kh*3 + kw)*CIN + cc)*COUT + co];
      }
    }
  out[idx] = s;
}

extern "C" void kernel_launch(void* const* d_in, const int* in_sizes, int n_in,
                              void* d_out, int out_size, void* d_ws, size_t ws_size,
                              hipStream_t stream) {
  const float* x = (const float*)d_in[0];
  const float* K = (const float*)d_in[1];
  float* out = (float*)d_out;
  if (ws_size >= WS_NEEDED) {
    __hip_bfloat16* xpT = (__hip_bfloat16*)d_ws;
    __hip_bfloat16* WgT = xpT + XP_TOTAL;
    prep_all<<<NROW + 1 + NWBLK, 256, 0, stream>>>(x, K, xpT, WgT);
    conv_mfma<<<B_*14, 256, 0, stream>>>(xpT, WgT, out);
  } else {
    conv_naive<<<(B_*COUT*H_*H_ + 255)/256, 256, 0, stream>>>(x, K, out);
  }
}